// Round 11
// baseline (654.878 us; speedup 1.0000x reference)
//
#include <hip/hip_runtime.h>

// TRGTMeanRelationBlock on MI355X (gfx950).
// Pipeline: prep(+cnt=0) ; node_pre(LN1 in-reg + Pd,Ps,Pm + aggf=0 + count) ;
//           scan_sums ; scan_final ; scatter(etab CSR) ; edge ; node_ffn
// Factorization: gate = f(Pd[dst]+Ps[src]+emb@We), msg1 = Pm[src]+emb@Me.
// Edge kernel: 8 waves = 2 Mg x 4 Ng (M=32, N=32); NO pre-compute barrier --
// every wave gathers etab/Pd/Ps/Pm/emb fragments directly from global (L2),
// folds P via identity-B MFMA, and runs to the t1/p_s exchange unsynced.
// Only t1 lives in LDS (cross-wave GEMM2 dep). 3 barriers total.
// Fragment layouts: A/B lane l -> (row/col = l&15, 8 contiguous k at (l>>4)*8).
//                   C/D lane l -> col = l&15, row = (l>>4)*4 + reg_idx.

typedef __attribute__((ext_vector_type(8))) short short8;
typedef __attribute__((ext_vector_type(4))) float f32x4;

#define NN 50000
#define NEDGE 800000

#define MFMA(a, b, c) __builtin_amdgcn_mfma_f32_16x16x32_bf16(a, b, c, 0, 0, 0)

__device__ __forceinline__ unsigned short f2bf(float f) {
  unsigned int u = __float_as_uint(f);
  u += 0x7fffu + ((u >> 16) & 1u);  // round-to-nearest-even
  return (unsigned short)(u >> 16);
}
__device__ __forceinline__ float bf2f(unsigned short u) {
  return __uint_as_float((unsigned int)u << 16);
}
__device__ __forceinline__ unsigned int cvtpk(float a, float b) {
  unsigned int d;  // d.lo = bf16(a), d.hi = bf16(b)
  asm("v_cvt_pk_bf16_f32 %0, %1, %2" : "=v"(d) : "v"(a), "v"(b));
  return d;
}
__device__ __forceinline__ unsigned short f2bf1(float a) {
  return (unsigned short)cvtpk(a, a);  // single-value RNE via HW cvt
}
// tanh-approx GELU, exp2-folded (|err| vs exact erf-GELU < 1e-3)
__device__ __forceinline__ float geluf(float x) {
  const float t = x * fmaf(-0.1029437f, x * x, -2.3022211f);
  return x * __builtin_amdgcn_rcpf(1.0f + exp2f(t));
}
__device__ __forceinline__ short8 ld8(const unsigned short* p) {
  return *reinterpret_cast<const short8*>(p);
}
__device__ __forceinline__ int swz256(int row, int byteoff) {  // 256 B rows
  return row * 256 + (byteoff ^ ((row & 15) << 4));
}

// In-register LayerNorm over a 128-col f32 row read in MFMA A-pattern.
__device__ __forceinline__ void ln_frags(const float* __restrict__ rowp,
                                         const float* __restrict__ g,
                                         const float* __restrict__ b, int koff,
                                         short8 a[4]) {
  f32x4 v[8];
#pragma unroll
  for (int s = 0; s < 4; s++) {
    v[2 * s] = *reinterpret_cast<const f32x4*>(rowp + s * 32 + koff);
    v[2 * s + 1] = *reinterpret_cast<const f32x4*>(rowp + s * 32 + koff + 4);
  }
  float sm = 0.f;
#pragma unroll
  for (int i = 0; i < 8; i++) sm += v[i][0] + v[i][1] + v[i][2] + v[i][3];
  sm += __shfl_xor(sm, 16);
  sm += __shfl_xor(sm, 32);
  const float mean = sm * 0.0078125f;
  float sq = 0.f;
#pragma unroll
  for (int i = 0; i < 8; i++) {
#pragma unroll
    for (int t = 0; t < 4; t++) {
      const float d = v[i][t] - mean;
      sq += d * d;
    }
  }
  sq += __shfl_xor(sq, 16);
  sq += __shfl_xor(sq, 32);
  const float rs = rsqrtf(sq * 0.0078125f + 1e-5f);
#pragma unroll
  for (int s = 0; s < 4; s++) {
    const f32x4 glo = *reinterpret_cast<const f32x4*>(g + s * 32 + koff);
    const f32x4 ghi = *reinterpret_cast<const f32x4*>(g + s * 32 + koff + 4);
    const f32x4 blo = *reinterpret_cast<const f32x4*>(b + s * 32 + koff);
    const f32x4 bhi = *reinterpret_cast<const f32x4*>(b + s * 32 + koff + 4);
    float y[8];
#pragma unroll
    for (int t = 0; t < 4; t++) {
      y[t] = (v[2 * s][t] - mean) * rs * glo[t] + blo[t];
      y[4 + t] = (v[2 * s + 1][t] - mean) * rs * ghi[t] + bhi[t];
    }
    union { unsigned int u[4]; short8 s8; } pk;
    pk.u[0] = cvtpk(y[0], y[1]);
    pk.u[1] = cvtpk(y[2], y[3]);
    pk.u[2] = cvtpk(y[4], y[5]);
    pk.u[3] = cvtpk(y[6], y[7]);
    a[s] = pk.s8;
  }
}

// ---- weight prep: transpose + f32->bf16. WT[n][k] = W[k][n]. Also zero cnt.
__global__ __launch_bounds__(256) void prep_kernel(
    const float* __restrict__ selfW, const float* __restrict__ msgW1,
    const float* __restrict__ msgW2, const float* __restrict__ gateW1,
    const float* __restrict__ aggW, const float* __restrict__ ffnW1,
    const float* __restrict__ ffnW2, unsigned short* __restrict__ wts,
    int* __restrict__ cnt) {
  const int idx = blockIdx.x * 256 + threadIdx.x;
  if (idx <= NN) cnt[idx] = 0;
  if (idx < 16384) {
    int n = idx >> 7, k = idx & 127;
    wts[idx] = f2bf(selfW[k * 128 + n]);
  } else if (idx < 32768) {
    int l = idx - 16384, n = l >> 7, k = l & 127;
    wts[idx] = f2bf(aggW[k * 128 + n]);
  } else if (idx < 57344) {
    int l = idx - 32768, n = l / 192, k = l - n * 192;
    wts[idx] = f2bf(msgW1[k * 128 + n]);
  } else if (idx < 73728) {
    int l = idx - 57344, n = l >> 7, k = l & 127;
    wts[idx] = f2bf(msgW2[k * 128 + n]);
  } else if (idx < 114688) {
    int l = idx - 73728, n = l / 320, k = l - n * 320;
    wts[idx] = f2bf(gateW1[k * 128 + n]);
  } else if (idx < 147456) {
    int l = idx - 114688, n = l >> 7, k = l & 127;
    wts[idx] = f2bf(ffnW1[k * 256 + n]);
  } else if (idx < 180224) {
    int l = idx - 147456, n = l >> 8, k = l & 255;
    wts[idx] = f2bf(ffnW2[k * 128 + n]);
  }
}

// ---- node precompute (LN1 fused): Pd/Ps/Pm (bf16) + zero aggf + edge count.
__global__ __launch_bounds__(256) void node_pre_kernel(
    const float* __restrict__ x, const float* __restrict__ ln1g,
    const float* __restrict__ ln1b, const unsigned short* __restrict__ wts,
    const int* __restrict__ edst, unsigned short* __restrict__ pd,
    unsigned short* __restrict__ psm, float* __restrict__ aggf,
    int* __restrict__ cnt) {
  const int wid = threadIdx.x >> 6, lane = threadIdx.x & 63;
  const int q = lane >> 4, r16 = lane & 15, koff = q * 8;
  const int r0 = blockIdx.x * 64 + wid * 16;
  const int row = min(r0 + r16, NN - 1);
  {
    const int t = blockIdx.x * 256 + threadIdx.x;
    const f32x4 z = (f32x4){0.f, 0.f, 0.f, 0.f};
#pragma unroll
    for (int k = 0; k < 8; k++) {
      const int pos = t + k * 200192;
      if (pos < NN * 32) reinterpret_cast<f32x4*>(aggf)[pos] = z;
    }
    // degree histogram (cnt pre-zeroed by prep_kernel, earlier on stream)
#pragma unroll
    for (int k = 0; k < 4; k++) {
      const int e = t + k * 200192;
      if (e < NEDGE) atomicAdd(&cnt[edst[e]], 1);
    }
  }
  const unsigned short* gateW1T = wts + 73728;  // [128][320]
  const unsigned short* msgW1T = wts + 32768;   // [128][192]
  short8 a[4];
  ln_frags(x + (size_t)row * 128, ln1g, ln1b, koff, a);
  f32x4 acc[3][8];
#pragma unroll
  for (int t = 0; t < 3; t++)
#pragma unroll
    for (int nt = 0; nt < 8; nt++) acc[t][nt] = (f32x4){0.f, 0.f, 0.f, 0.f};
#pragma unroll
  for (int s = 0; s < 4; s++) {
    const int k0 = s * 32 + koff;
#pragma unroll
    for (int nt = 0; nt < 8; nt++) {
      const int c = nt * 16 + r16;
      acc[0][nt] = MFMA(a[s], ld8(gateW1T + c * 320 + k0), acc[0][nt]);
      acc[1][nt] = MFMA(a[s], ld8(gateW1T + c * 320 + 128 + k0), acc[1][nt]);
      acc[2][nt] = MFMA(a[s], ld8(msgW1T + c * 192 + k0), acc[2][nt]);
    }
  }
#pragma unroll
  for (int j = 0; j < 4; j++) {
    const int gr = r0 + q * 4 + j;
    if (gr < NN) {
#pragma unroll
      for (int nt = 0; nt < 8; nt++) {
        const int c = nt * 16 + r16;
        pd[(size_t)gr * 128 + c] = f2bf(acc[0][nt][j]);
        psm[(size_t)gr * 256 + c] = f2bf(acc[1][nt][j]);
        psm[(size_t)gr * 256 + 128 + c] = f2bf(acc[2][nt][j]);
      }
    }
  }
}

// ---- CSR build ----
__global__ __launch_bounds__(256) void scan_sums_kernel(
    const int* __restrict__ cnt, int* __restrict__ bsum) {
  const int gi = blockIdx.x * 256 + threadIdx.x;
  int v = (gi < NN) ? cnt[gi] : 0;
#pragma unroll
  for (int m = 1; m < 64; m <<= 1) v += __shfl_xor(v, m);
  __shared__ int wsum[4];
  if ((threadIdx.x & 63) == 0) wsum[threadIdx.x >> 6] = v;
  __syncthreads();
  if (threadIdx.x == 0)
    bsum[blockIdx.x] = wsum[0] + wsum[1] + wsum[2] + wsum[3];
}

// final: row_start (exclusive) + cursor; block offset computed inline from bsum
__global__ __launch_bounds__(256) void scan_final_kernel(
    const int* __restrict__ cnt, const int* __restrict__ bsum,
    int* __restrict__ row_start, int* __restrict__ cursor) {
  const int tid = threadIdx.x, lane = tid & 63, wid = tid >> 6;
  const int gi = blockIdx.x * 256 + tid;
  __shared__ int boff_s;
  __shared__ int wsum[4];
  if (wid == 0) {
    int pre = 0;
    for (int i = lane; i < blockIdx.x; i += 64) pre += bsum[i];
#pragma unroll
    for (int m = 32; m >= 1; m >>= 1) pre += __shfl_xor(pre, m);
    if (lane == 0) boff_s = pre;
  }
  const int val = (gi < NN) ? cnt[gi] : 0;
  int v = val;
#pragma unroll
  for (int d = 1; d < 64; d <<= 1) {
    const int t = __shfl_up(v, d);
    if (lane >= d) v += t;
  }
  if (lane == 63) wsum[wid] = v;
  __syncthreads();
  int woff = 0;
  for (int w = 0; w < wid; ++w) woff += wsum[w];
  const int excl = (v - val) + woff + boff_s;
  if (gi < NN) {
    row_start[gi] = excl;
    cursor[gi] = excl;
  }
  if (gi == NN - 1) row_start[NN] = excl + val;
}

// scatter: build packed per-CSR-slot edge table {e, si, di, sc}
__global__ __launch_bounds__(256) void scatter_kernel(
    const int* __restrict__ esrc, const int* __restrict__ edst,
    const float* __restrict__ tw, const float* __restrict__ mns,
    int* __restrict__ cursor, int4* __restrict__ etab) {
  const int e = blockIdx.x * 256 + threadIdx.x;
  const int si = esrc[e];
  const int di = edst[e];
  const int pos = atomicAdd(&cursor[di], 1);
  const float sc = tw[e] * 0.5f * (mns[si] + mns[di]);
  int4 v;
  v.x = e;
  v.y = si;
  v.z = di;
  v.w = __float_as_int(sc);
  etab[pos] = v;
}

// ---- edge kernel: 64 CSR-ordered edges/block; 8 waves = 2 Mg x 4 Ng
// (M=32, N=32 each); all inputs gathered directly from global; only t1 in
// LDS; 3 barriers.
__global__ __launch_bounds__(512, 6) void edge_kernel(
    const float* __restrict__ emb, const int4* __restrict__ etab,
    const unsigned short* __restrict__ pd,
    const unsigned short* __restrict__ psm,
    const unsigned short* __restrict__ wts, const float* __restrict__ msgb1,
    const float* __restrict__ msgb2, const float* __restrict__ gateb1,
    const float* __restrict__ gateW2, const float* __restrict__ gateb2v,
    float* __restrict__ erout, float* __restrict__ aggf) {
  // t1 [0,16384) swz256 ; f32 xbuf [64][132] = [0,33792) aliases it in the
  // epilogue (xbuf writes only after barrier B, when t1 reads are done).
  __shared__ __align__(16) char buf[33792];
  __shared__ float p_s[4][64];
  __shared__ float G_s[64];
  __shared__ float sc_s[64];
  __shared__ int di_s[64], eidx_s[64];

  char* t1p = buf;
  float* xbuf = (float*)buf;

  const int tid = threadIdx.x;
  const int lane = tid & 63;
  const int wid = tid >> 6;
  const int q = lane >> 4;
  const int r16 = lane & 15;
  const int koff = q * 8;
  const int mg = wid >> 2;  // 0..1
  const int ng = wid & 3;   // 0..3
  const int e0 = blockIdx.x * 64;  // CSR positions; 12500*64 == NEDGE

  const unsigned short* gateW1T = wts + 73728;  // [128][320]
  const unsigned short* msgW1T = wts + 32768;   // [128][192]
  const unsigned short* msgW2T = wts + 57344;   // [128][128]

  // ---- per-edge scalars. NO barrier: di_s/eidx_s consumed after barrier C,
  // sc_s after barrier A (tid<64 writes, tid<64 reads -- same threads).
  if (tid < 64) {
    const int4 et = etab[e0 + tid];
    eidx_s[tid] = et.x;
    di_s[tid] = et.z;
    sc_s[tid] = __int_as_float(et.w);
  }

  // ---- per-wave direct gathers: etab rows for this wave's two m-tiles
  int4 et[2];
#pragma unroll
  for (int m = 0; m < 2; m++)
    et[m] = etab[e0 + mg * 32 + m * 16 + r16];

  int cc[2];
  float g1[2], w2[2], b1m[2], b2m[2];
#pragma unroll
  for (int i = 0; i < 2; i++) {
    cc[i] = ng * 32 + i * 16 + r16;
    g1[i] = gateb1[cc[i]];
    w2[i] = gateW2[cc[i]];
    b1m[i] = msgb1[cc[i]];
    b2m[i] = msgb2[cc[i]];
  }

  // identity-B fragments: bI[i][h] = 1.0bf16 iff (q*8+h == i*16 + r16).
  short8 bI[2];
#pragma unroll
  for (int h = 0; h < 8; h++) {
    const int kk = koff + h;
    bI[0][h] = (kk == r16) ? (short)0x3F80 : (short)0;
    bI[1][h] = (kk == r16 + 16) ? (short)0x3F80 : (short)0;
  }

  f32x4 accg[2][2], acc1[2][2];
#pragma unroll
  for (int m = 0; m < 2; m++)
#pragma unroll
    for (int i = 0; i < 2; i++) {
      accg[m][i] = (f32x4){0.f, 0.f, 0.f, 0.f};
      acc1[m][i] = (f32x4){0.f, 0.f, 0.f, 0.f};
    }

  // ---- fold Pd[di], Ps[si] into accg and Pm[si] into acc1 via @Identity.
  // Wave (mg,ng)'s output cols live in K-window ng*32 -> direct global ld8.
  {
    const int kw = ng * 32 + koff;
#pragma unroll
    for (int m = 0; m < 2; m++) {
      const short8 apd = ld8(pd + (size_t)et[m].z * 128 + kw);
      const short8 aps = ld8(psm + (size_t)et[m].y * 256 + kw);
      const short8 apm = ld8(psm + (size_t)et[m].y * 256 + 128 + kw);
#pragma unroll
      for (int i = 0; i < 2; i++) {
        accg[m][i] = MFMA(apd, bI[i], accg[m][i]);
        accg[m][i] = MFMA(aps, bI[i], accg[m][i]);
        acc1[m][i] = MFMA(apm, bI[i], acc1[m][i]);
      }
    }
  }

  // ---- emb GEMMs: accg += emb@We (K=64), acc1 += emb@Me (K=64).
  // A-fragments built directly from global f32 (L2-hot within the block).
#pragma unroll
  for (int s = 0; s < 2; s++) {
    const int k0 = s * 32 + koff;  // 0..63
    short8 a[2];
#pragma unroll
    for (int m = 0; m < 2; m++) {
      const float* ep = emb + (size_t)et[m].x * 64 + k0;
      const f32x4 v0 = *reinterpret_cast<const f32x4*>(ep);
      const f32x4 v1 = *reinterpret_cast<const f32x4*>(ep + 4);
      union { unsigned int u[4]; short8 s8; } pk;
      pk.u[0] = cvtpk(v0[0], v0[1]);
      pk.u[1] = cvtpk(v0[2], v0[3]);
      pk.u[2] = cvtpk(v1[0], v1[1]);
      pk.u[3] = cvtpk(v1[2], v1[3]);
      a[m] = pk.s8;
    }
#pragma unroll
    for (int i = 0; i < 2; i++) {
      const short8 bg = ld8(gateW1T + cc[i] * 320 + 256 + k0);
      const short8 bm = ld8(msgW1T + cc[i] * 192 + 128 + k0);
#pragma unroll
      for (int m = 0; m < 2; m++) {
        accg[m][i] = MFMA(a[m], bg, accg[m][i]);
        acc1[m][i] = MFMA(a[m], bm, acc1[m][i]);
      }
    }
  }

  // ---- gate partials over this wave's 32 cols
#pragma unroll
  for (int m = 0; m < 2; m++) {
#pragma unroll
    for (int j = 0; j < 4; j++) {
      const int row = mg * 32 + m * 16 + q * 4 + j;
      float v = geluf(accg[m][0][j] + g1[0]) * w2[0] +
                geluf(accg[m][1][j] + g1[1]) * w2[1];
      v += __shfl_xor(v, 1);
      v += __shfl_xor(v, 2);
      v += __shfl_xor(v, 4);
      v += __shfl_xor(v, 8);
      if (r16 == 0) p_s[ng][row] = v;
    }
  }

  // ---- t1 = gelu(acc1 + b1) -> write-only into t1 tile
#pragma unroll
  for (int m = 0; m < 2; m++) {
#pragma unroll
    for (int i = 0; i < 2; i++) {
#pragma unroll
      for (int j = 0; j < 4; j++) {
        const int row = mg * 32 + m * 16 + q * 4 + j;
        *reinterpret_cast<unsigned short*>(t1p + swz256(row, cc[i] * 2)) =
            f2bf1(geluf(acc1[m][i][j] + b1m[i]));
      }
    }
  }
  __syncthreads();  // (A) t1 + p_s ready

  // ---- G combine (runs alongside GEMM2)
  if (tid < 64) {
    const float p = gateb2v[0] + p_s[0][tid] + p_s[1][tid] + p_s[2][tid] +
                    p_s[3][tid];
    G_s[tid] =
        sc_s[tid] * __builtin_amdgcn_rcpf(1.f + exp2f(-1.4426950f * p));
  }

  // ---- msg GEMM2: t1 @ msgW2, K=128
  f32x4 acc2[2][2];
#pragma unroll
  for (int m = 0; m < 2; m++)
#pragma unroll
    for (int i = 0; i < 2; i++) acc2[m][i] = (f32x4){0.f, 0.f, 0.f, 0.f};
#pragma unroll
  for (int s = 0; s < 4; s++) {
    const int k0 = s * 32 + koff;
    short8 a[2];
#pragma unroll
    for (int m = 0; m < 2; m++)
      a[m] = *reinterpret_cast<const short8*>(
          t1p + swz256(mg * 32 + m * 16 + r16, k0 * 2));
#pragma unroll
    for (int i = 0; i < 2; i++) {
      const short8 b = ld8(msgW2T + cc[i] * 128 + k0);
#pragma unroll
      for (int m = 0; m < 2; m++) acc2[m][i] = MFMA(a[m], b, acc2[m][i]);
    }
  }
  __syncthreads();  // (B) all t1 reads done; G_s ready; xbuf safe

  // ---- epilogue: scale + single-pass transpose into xbuf[64][132]
#pragma unroll
  for (int m = 0; m < 2; m++)
#pragma unroll
    for (int i = 0; i < 2; i++)
#pragma unroll
      for (int j = 0; j < 4; j++) {
        const int row = mg * 32 + m * 16 + q * 4 + j;
        xbuf[row * 132 + cc[i]] = G_s[row] * (acc2[m][i][j] + b2m[i]);
      }
  __syncthreads();  // (C) xbuf complete

  // full-line float4 stores to the (original edge id) output rows
#pragma unroll
  for (int u = 0; u < 4; u++) {
    const int unit = tid + u * 512;  // 0..2047 = 64 rows x 32 f4-chunks
    const int r = unit >> 5;
    const int f4 = unit & 31;
    const f32x4 val = *reinterpret_cast<const f32x4*>(&xbuf[r * 132 + f4 * 4]);
    *reinterpret_cast<f32x4*>(erout + (size_t)eidx_s[r] * 128 + f4 * 4) = val;
  }

  // segmented column-walk aggregation (rows are dst-sorted):
  // 512 threads = 128 cols x 4 sixteen-row quarters; ~1-3 flushes per quarter.
  {
    const int col = tid & 127;
    const int qt = tid >> 7;  // 0..3
    const int rbeg = qt * 16, rend = rbeg + 16;
    float acc = 0.f;
    int prev = di_s[rbeg];
    for (int r = rbeg; r < rend; ++r) {
      const int d = di_s[r];
      if (d != prev) {
        atomicAdd(&aggf[(size_t)prev * 128 + col], acc);
        acc = 0.f;
        prev = d;
      }
      acc += xbuf[r * 132 + col];
    }
    atomicAdd(&aggf[(size_t)prev * 128 + col], acc);
  }
}

// ---- fused node update + FFN:
// out1 = x + LN1(x)@selfW + selfb + (agg/deg)@aggW + aggb   (registers only)
// out  = out1 + gelu(LN2(out1)@W1 + b1)@W2 + b2
__global__ __launch_bounds__(256) void node_ffn_kernel(
    const float* __restrict__ x, const float* __restrict__ ln1g,
    const float* __restrict__ ln1b, const float* __restrict__ aggf,
    const int* __restrict__ row_start, const unsigned short* __restrict__ wts,
    const float* __restrict__ selfb, const float* __restrict__ aggb,
    const float* __restrict__ ln2g, const float* __restrict__ ln2b,
    const float* __restrict__ fb1, const float* __restrict__ fb2,
    float* __restrict__ outp) {
  __shared__ unsigned short h2s[4][16 * 136];  // LN2 output per wave
  __shared__ unsigned short ts[4][16 * 264];   // gelu(t) per wave
  const int wid = threadIdx.x >> 6, lane = threadIdx.x & 63;
  const int q = lane >> 4, r16 = lane & 15, koff = q * 8;
  const int r0 = blockIdx.x * 64 + wid * 16;
  const int row = min(r0 + r16, NN - 1);
  const float inv = __builtin_amdgcn_rcpf(
      fmaxf((float)(row_start[row + 1] - row_start[row]), 1.0f));
  const unsigned short* selfWT = wts;
  const unsigned short* aggWT = wts + 16384;
  const unsigned short* W1T = wts + 114688;  // [256][128]
  const unsigned short* W2T = wts + 147456;  // [128][256]

  // ---- node1 GEMMs
  short8 a1[4];
  ln_frags(x + (size_t)row * 128, ln1g, ln1b, koff, a1);
  f32x4 acc[8];
#pragma unroll
  for (int nt = 0; nt < 8; nt++) acc[nt] = (f32x4){0.f, 0.f, 0.f, 0.f};
#pragma unroll
  for (int s = 0; s < 4; s++) {
    const int k0 = s * 32 + koff;
    const float* ap = aggf + (size_t)row * 128 + k0;
    const f32x4 f0 = *reinterpret_cast<const f32x4*>(ap);
    const f32x4 f1 = *reinterpret_cast<const f32x4*>(ap + 4);
    union { unsigned int u[4]; short8 s; } pk;
    pk.u[0] = cvtpk(f0[0] * inv, f0[1] * inv);
    pk.u[1] = cvtpk(f0[2] * inv, f0[3] * inv);
    pk.u[2] = cvtpk(f1[0] * inv, f1[1] * inv);
    pk.u[3] = cvtpk(f1[2] * inv, f1[3] * inv);
#pragma unroll
    for (int nt = 0; nt < 8; nt++) {
      acc[nt] = MFMA(a1[s], ld8(selfWT + (nt * 16 + r16) * 128 + k0), acc[nt]);
      acc[nt] = MFMA(pk.s, ld8(aggWT + (nt * 16 + r16) * 128 + k0), acc[nt]);
    }
  }

  // ---- out1 in registers (C/D layout: o[nt][j], col = nt*16+r16, row q*4+j)
  float o[8][4];
#pragma unroll
  for (int j = 0; j < 4; j++) {
    const int gr = min(r0 + q * 4 + j, NN - 1);
#pragma unroll
    for (int nt = 0; nt < 8; nt++) {
      const int c = r16 + 16 * nt;
      o[nt][j] = x[(size_t)gr * 128 + c] + acc[nt][j] + selfb[c] + aggb[c];
    }
  }

  // ---- LN2 in C/D layout (reduce over 16 r16-lanes x 8 nt) -> h2s bf16
#pragma unroll
  for (int j = 0; j < 4; j++) {
    float s1 = 0.f;
#pragma unroll
    for (int nt = 0; nt < 8; nt++) s1 += o[nt][j];
    s1 += __shfl_xor(s1, 1);
    s1 += __shfl_xor(s1, 2);
    s1 += __shfl_xor(s1, 4);
    s1 += __shfl_xor(s1, 8);
    const float mean = s1 * 0.0078125f;
    float s2 = 0.f;
#pragma unroll
    for (int nt = 0; nt < 8; nt++) {
      const float d = o[nt][j] - mean;
      s2 += d * d;
    }
    s2 += __shfl_xor(s2, 1);
    s2 += __shfl_xor(s2, 2);
    s2 += __shfl_xor(s2, 4);
    s2 += __shfl_xor(s2, 8);
    const float rs = rsqrtf(s2 * 0.0078125f + 1e-5f);
#pragma unroll
    for (int nt = 0; nt < 8; nt++) {
      const int c = r16 + 16 * nt;
      h2s[wid][(q * 4 + j) * 136 + c] =
          f2bf1((o[nt][j] - mean) * rs * ln2g[c] + ln2b[c]);
    }
  }
  // wave-local LDS dep (writer lanes != reader lanes but same wave: lgkmcnt)

  // ---- FFN GEMM1: h2 @ W1 (K=128, N=256)
  f32x4 acc1[16];
#pragma unroll
  for (int nt = 0; nt < 16; nt++) acc1[nt] = (f32x4){0.f, 0.f, 0.f, 0.f};
#pragma unroll
  for (int s = 0; s < 4; s++) {
    const int k0 = s * 32 + koff;
    const short8 a =
        *reinterpret_cast<const short8*>(&h2s[wid][r16 * 136 + k0]);
#pragma unroll
    for (int nt = 0; nt < 16; nt++)
      acc1[nt] = MFMA(a, ld8(W1T + (nt * 16 + r16) * 128 + k0), acc1[nt]);
  }
#pragma unroll
  for (int nt = 0; nt < 16; nt++) {
    const int c = r16 + 16 * nt;
    const float bb = fb1[c];
#pragma unroll
    for (int j = 0; j < 4; j++)
      ts[wid][(q * 4 + j) * 264 + c] = f2bf1(geluf(acc1[nt][j] + bb));
  }

  // ---- FFN GEMM2: t @ W2 (K=256, N=128), wave-local ts
  f32x4 acc2[8];
#pragma unroll
  for (int nt = 0; nt < 8; nt++) acc2[nt] = (f32x4){0.f, 0.f, 0.f, 0.f};
#pragma unroll
  for (int s = 0; s < 8; s++) {
    const int k0 = s * 32 + koff;
    const short8 av =
        *reinterpret_cast<const short8*>(&ts[wid][r16 * 264 + k0]);
#pragma unroll
    for (int nt = 0; nt < 8; nt++)
      acc2[nt] = MFMA(av, ld8(W2T + (nt * 16 + r16) * 256 + k0), acc2[nt]);
  }

  // ---- final: out = out1 + ffn + b2
#pragma unroll
  for (int j = 0; j < 4; j++) {
    const int gr = r0 + q * 4 + j;
    if (gr < NN) {
#pragma unroll
      for (int nt = 0; nt < 8; nt++) {
        const int c = r16 + 16 * nt;
        outp[(size_t)gr * 128 + c] = o[nt][j] + acc2[nt][j] + fb2[c];
      }
    }
  }
}

extern "C" void kernel_launch(void* const* d_in, const int* in_sizes, int n_in,
                              void* d_out, int out_size, void* d_ws,
                              size_t ws_size, hipStream_t stream) {
  (void)in_sizes; (void)n_in; (void)out_size; (void)ws_size;
  const float* x = (const float*)d_in[0];
  const float* emb = (const float*)d_in[1];
  const float* tw = (const float*)d_in[2];
  const float* mns = (const float*)d_in[3];
  const float* ln1g = (const float*)d_in[4];
  const float* ln1b = (const float*)d_in[5];
  const float* ln2g = (const float*)d_in[6];
  const float* ln2b = (const float*)d_in[7];
  const float* selfW = (const float*)d_in[8];
  const float* selfb = (const float*)d_in[9];
  const float* msgW1 = (const float*)d_in[10];
  const float* msgb1 = (const float*)d_in[11];
  const float* msgW2 = (const float*)d_in[12];
  const float* msgb2 = (const float*)d_in[13];
  const float* gateW1 = (const float*)d_in[14];
  const float* gateb1 = (const float*)d_in[15];
  const float* gateW2 = (const float*)d_in[16];
  const float* gateb2 = (const float*)d_in[17];
  const float* aggW = (const float*)d_in[18];
  const float* aggb = (const float*)d_in[19];
  const float* ffnW1 = (const float*)d_in[20];
  const float* ffnb1 = (const float*)d_in[21];
  const float* ffnW2 = (const float*)d_in[22];
  const float* ffnb2 = (const float*)d_in[23];
  const int* esrc = (const int*)d_in[24];
  const int* edst = (const int*)d_in[25];

  // ws layout (bytes):
  // Pd 0..12.8M | Psm 25.6M..51.2M | wts 76.8M+360448 | cnt 77,160,448 |
  // row_start 77,360,640 | cursor 77,560,832 | bsum 77,761,024 |
  // etab 77,763,072 +12.8M (~90.6 MB)
  // agg accumulator lives in d_out's NODE region (dead until node_ffn).
  char* ws = (char*)d_ws;
  unsigned short* pdb = (unsigned short*)(ws);
  unsigned short* psmb = (unsigned short*)(ws + 25600000);
  unsigned short* wts = (unsigned short*)(ws + 76800000);
  int* cnt = (int*)(ws + 77160448);
  int* row_start = (int*)(ws + 77360640);
  int* cursor = (int*)(ws + 77560832);
  int* bsum = (int*)(ws + 77761024);
  int4* etab = (int4*)(ws + 77763072);

  float* out_nodes = (float*)d_out;
  float* out_edges = out_nodes + (size_t)NN * 128;
  float* aggf = out_nodes;  // reused as f32 accumulator until node_ffn

  const int NB_SCAN = (NN + 255) / 256;  // 196

  prep_kernel<<<704, 256, 0, stream>>>(selfW, msgW1, msgW2, gateW1, aggW,
                                       ffnW1, ffnW2, wts, cnt);
  node_pre_kernel<<<782, 256, 0, stream>>>(x, ln1g, ln1b, wts, edst, pdb,
                                           psmb, aggf, cnt);
  scan_sums_kernel<<<NB_SCAN, 256, 0, stream>>>(cnt, bsum);
  scan_final_kernel<<<NB_SCAN, 256, 0, stream>>>(cnt, bsum, row_start, cursor);
  scatter_kernel<<<3125, 256, 0, stream>>>(esrc, edst, tw, mns, cursor, etab);
  edge_kernel<<<12500, 512, 0, stream>>>(emb, etab, pdb, psmb, wts, msgb1,
                                         msgb2, gateb1, gateW2, gateb2,
                                         out_edges, aggf);
  node_ffn_kernel<<<782, 256, 0, stream>>>(x, ln1g, ln1b, aggf, row_start,
                                           wts, selfb, aggb, ln2g, ln2b,
                                           ffnb1, ffnb2, out_nodes);
}

// Round 12
// 581.580 us; speedup vs baseline: 1.1260x; 1.1260x over previous
//
#include <hip/hip_runtime.h>

// TRGTMeanRelationBlock on MI355X (gfx950).
// Pipeline: prep(+cnt=0) ; node_pre(LN1 in-reg + Pd,Ps,Pm + aggf=0 + count) ;
//           scan_sums ; scan_final ; scatter(etab CSR) ; edge ; node_ffn
// Factorization: gate = f(Pd[dst]+Ps[src]+emb@We), msg1 = Pm[src]+emb@Me.
// Edge kernel (best measured config, R9): 64 CSR-ordered edges/block,
// 8 waves = 2 Mg x 4 Ng (M=32, N=32); pg=bf16(Pd+Ps)/pm/emb cooperatively
// staged in LDS (b128 writes, XOR swizzle); P folded into MFMA accumulators
// via IDENTITY-B MFMA (1 ds_read_b128 + 2 MFMA per subtile); fused
// segmented-atomic aggregation. 4 barriers.
// Fragment layouts: A/B lane l -> (row/col = l&15, 8 contiguous k at (l>>4)*8).
//                   C/D lane l -> col = l&15, row = (l>>4)*4 + reg_idx.

typedef __attribute__((ext_vector_type(8))) short short8;
typedef __attribute__((ext_vector_type(4))) float f32x4;

#define NN 50000
#define NEDGE 800000

#define MFMA(a, b, c) __builtin_amdgcn_mfma_f32_16x16x32_bf16(a, b, c, 0, 0, 0)

__device__ __forceinline__ unsigned short f2bf(float f) {
  unsigned int u = __float_as_uint(f);
  u += 0x7fffu + ((u >> 16) & 1u);  // round-to-nearest-even
  return (unsigned short)(u >> 16);
}
__device__ __forceinline__ float bf2f(unsigned short u) {
  return __uint_as_float((unsigned int)u << 16);
}
__device__ __forceinline__ unsigned int cvtpk(float a, float b) {
  unsigned int d;  // d.lo = bf16(a), d.hi = bf16(b)
  asm("v_cvt_pk_bf16_f32 %0, %1, %2" : "=v"(d) : "v"(a), "v"(b));
  return d;
}
__device__ __forceinline__ unsigned short f2bf1(float a) {
  return (unsigned short)cvtpk(a, a);  // single-value RNE via HW cvt
}
// tanh-approx GELU, exp2-folded (|err| vs exact erf-GELU < 1e-3)
__device__ __forceinline__ float geluf(float x) {
  const float t = x * fmaf(-0.1029437f, x * x, -2.3022211f);
  return x * __builtin_amdgcn_rcpf(1.0f + exp2f(t));
}
__device__ __forceinline__ short8 ld8(const unsigned short* p) {
  return *reinterpret_cast<const short8*>(p);
}
__device__ __forceinline__ int swz256(int row, int byteoff) {  // 256 B rows
  return row * 256 + (byteoff ^ ((row & 15) << 4));
}
__device__ __forceinline__ int swz128(int row, int byteoff) {  // 128 B rows
  return row * 128 + (byteoff ^ ((row & 7) << 4));
}

// In-register LayerNorm over a 128-col f32 row read in MFMA A-pattern.
__device__ __forceinline__ void ln_frags(const float* __restrict__ rowp,
                                         const float* __restrict__ g,
                                         const float* __restrict__ b, int koff,
                                         short8 a[4]) {
  f32x4 v[8];
#pragma unroll
  for (int s = 0; s < 4; s++) {
    v[2 * s] = *reinterpret_cast<const f32x4*>(rowp + s * 32 + koff);
    v[2 * s + 1] = *reinterpret_cast<const f32x4*>(rowp + s * 32 + koff + 4);
  }
  float sm = 0.f;
#pragma unroll
  for (int i = 0; i < 8; i++) sm += v[i][0] + v[i][1] + v[i][2] + v[i][3];
  sm += __shfl_xor(sm, 16);
  sm += __shfl_xor(sm, 32);
  const float mean = sm * 0.0078125f;
  float sq = 0.f;
#pragma unroll
  for (int i = 0; i < 8; i++) {
#pragma unroll
    for (int t = 0; t < 4; t++) {
      const float d = v[i][t] - mean;
      sq += d * d;
    }
  }
  sq += __shfl_xor(sq, 16);
  sq += __shfl_xor(sq, 32);
  const float rs = rsqrtf(sq * 0.0078125f + 1e-5f);
#pragma unroll
  for (int s = 0; s < 4; s++) {
    const f32x4 glo = *reinterpret_cast<const f32x4*>(g + s * 32 + koff);
    const f32x4 ghi = *reinterpret_cast<const f32x4*>(g + s * 32 + koff + 4);
    const f32x4 blo = *reinterpret_cast<const f32x4*>(b + s * 32 + koff);
    const f32x4 bhi = *reinterpret_cast<const f32x4*>(b + s * 32 + koff + 4);
    float y[8];
#pragma unroll
    for (int t = 0; t < 4; t++) {
      y[t] = (v[2 * s][t] - mean) * rs * glo[t] + blo[t];
      y[4 + t] = (v[2 * s + 1][t] - mean) * rs * ghi[t] + bhi[t];
    }
    union { unsigned int u[4]; short8 s8; } pk;
    pk.u[0] = cvtpk(y[0], y[1]);
    pk.u[1] = cvtpk(y[2], y[3]);
    pk.u[2] = cvtpk(y[4], y[5]);
    pk.u[3] = cvtpk(y[6], y[7]);
    a[s] = pk.s8;
  }
}

// ---- weight prep: transpose + f32->bf16. WT[n][k] = W[k][n]. Also zero cnt.
__global__ __launch_bounds__(256) void prep_kernel(
    const float* __restrict__ selfW, const float* __restrict__ msgW1,
    const float* __restrict__ msgW2, const float* __restrict__ gateW1,
    const float* __restrict__ aggW, const float* __restrict__ ffnW1,
    const float* __restrict__ ffnW2, unsigned short* __restrict__ wts,
    int* __restrict__ cnt) {
  const int idx = blockIdx.x * 256 + threadIdx.x;
  if (idx <= NN) cnt[idx] = 0;
  if (idx < 16384) {
    int n = idx >> 7, k = idx & 127;
    wts[idx] = f2bf(selfW[k * 128 + n]);
  } else if (idx < 32768) {
    int l = idx - 16384, n = l >> 7, k = l & 127;
    wts[idx] = f2bf(aggW[k * 128 + n]);
  } else if (idx < 57344) {
    int l = idx - 32768, n = l / 192, k = l - n * 192;
    wts[idx] = f2bf(msgW1[k * 128 + n]);
  } else if (idx < 73728) {
    int l = idx - 57344, n = l >> 7, k = l & 127;
    wts[idx] = f2bf(msgW2[k * 128 + n]);
  } else if (idx < 114688) {
    int l = idx - 73728, n = l / 320, k = l - n * 320;
    wts[idx] = f2bf(gateW1[k * 128 + n]);
  } else if (idx < 147456) {
    int l = idx - 114688, n = l >> 7, k = l & 127;
    wts[idx] = f2bf(ffnW1[k * 256 + n]);
  } else if (idx < 180224) {
    int l = idx - 147456, n = l >> 8, k = l & 255;
    wts[idx] = f2bf(ffnW2[k * 128 + n]);
  }
}

// ---- node precompute (LN1 fused): Pd/Ps/Pm (bf16) + zero aggf + edge count.
__global__ __launch_bounds__(256) void node_pre_kernel(
    const float* __restrict__ x, const float* __restrict__ ln1g,
    const float* __restrict__ ln1b, const unsigned short* __restrict__ wts,
    const int* __restrict__ edst, unsigned short* __restrict__ pd,
    unsigned short* __restrict__ psm, float* __restrict__ aggf,
    int* __restrict__ cnt) {
  const int wid = threadIdx.x >> 6, lane = threadIdx.x & 63;
  const int q = lane >> 4, r16 = lane & 15, koff = q * 8;
  const int r0 = blockIdx.x * 64 + wid * 16;
  const int row = min(r0 + r16, NN - 1);
  {
    const int t = blockIdx.x * 256 + threadIdx.x;
    const f32x4 z = (f32x4){0.f, 0.f, 0.f, 0.f};
#pragma unroll
    for (int k = 0; k < 8; k++) {
      const int pos = t + k * 200192;
      if (pos < NN * 32) reinterpret_cast<f32x4*>(aggf)[pos] = z;
    }
    // degree histogram (cnt pre-zeroed by prep_kernel, earlier on stream)
#pragma unroll
    for (int k = 0; k < 4; k++) {
      const int e = t + k * 200192;
      if (e < NEDGE) atomicAdd(&cnt[edst[e]], 1);
    }
  }
  const unsigned short* gateW1T = wts + 73728;  // [128][320]
  const unsigned short* msgW1T = wts + 32768;   // [128][192]
  short8 a[4];
  ln_frags(x + (size_t)row * 128, ln1g, ln1b, koff, a);
  f32x4 acc[3][8];
#pragma unroll
  for (int t = 0; t < 3; t++)
#pragma unroll
    for (int nt = 0; nt < 8; nt++) acc[t][nt] = (f32x4){0.f, 0.f, 0.f, 0.f};
#pragma unroll
  for (int s = 0; s < 4; s++) {
    const int k0 = s * 32 + koff;
#pragma unroll
    for (int nt = 0; nt < 8; nt++) {
      const int c = nt * 16 + r16;
      acc[0][nt] = MFMA(a[s], ld8(gateW1T + c * 320 + k0), acc[0][nt]);
      acc[1][nt] = MFMA(a[s], ld8(gateW1T + c * 320 + 128 + k0), acc[1][nt]);
      acc[2][nt] = MFMA(a[s], ld8(msgW1T + c * 192 + k0), acc[2][nt]);
    }
  }
#pragma unroll
  for (int j = 0; j < 4; j++) {
    const int gr = r0 + q * 4 + j;
    if (gr < NN) {
#pragma unroll
      for (int nt = 0; nt < 8; nt++) {
        const int c = nt * 16 + r16;
        pd[(size_t)gr * 128 + c] = f2bf(acc[0][nt][j]);
        psm[(size_t)gr * 256 + c] = f2bf(acc[1][nt][j]);
        psm[(size_t)gr * 256 + 128 + c] = f2bf(acc[2][nt][j]);
      }
    }
  }
}

// ---- CSR build ----
__global__ __launch_bounds__(256) void scan_sums_kernel(
    const int* __restrict__ cnt, int* __restrict__ bsum) {
  const int gi = blockIdx.x * 256 + threadIdx.x;
  int v = (gi < NN) ? cnt[gi] : 0;
#pragma unroll
  for (int m = 1; m < 64; m <<= 1) v += __shfl_xor(v, m);
  __shared__ int wsum[4];
  if ((threadIdx.x & 63) == 0) wsum[threadIdx.x >> 6] = v;
  __syncthreads();
  if (threadIdx.x == 0)
    bsum[blockIdx.x] = wsum[0] + wsum[1] + wsum[2] + wsum[3];
}

// final: row_start (exclusive) + cursor; block offset computed inline from bsum
__global__ __launch_bounds__(256) void scan_final_kernel(
    const int* __restrict__ cnt, const int* __restrict__ bsum,
    int* __restrict__ row_start, int* __restrict__ cursor) {
  const int tid = threadIdx.x, lane = tid & 63, wid = tid >> 6;
  const int gi = blockIdx.x * 256 + tid;
  __shared__ int boff_s;
  __shared__ int wsum[4];
  if (wid == 0) {
    int pre = 0;
    for (int i = lane; i < blockIdx.x; i += 64) pre += bsum[i];
#pragma unroll
    for (int m = 32; m >= 1; m >>= 1) pre += __shfl_xor(pre, m);
    if (lane == 0) boff_s = pre;
  }
  const int val = (gi < NN) ? cnt[gi] : 0;
  int v = val;
#pragma unroll
  for (int d = 1; d < 64; d <<= 1) {
    const int t = __shfl_up(v, d);
    if (lane >= d) v += t;
  }
  if (lane == 63) wsum[wid] = v;
  __syncthreads();
  int woff = 0;
  for (int w = 0; w < wid; ++w) woff += wsum[w];
  const int excl = (v - val) + woff + boff_s;
  if (gi < NN) {
    row_start[gi] = excl;
    cursor[gi] = excl;
  }
  if (gi == NN - 1) row_start[NN] = excl + val;
}

// scatter: build packed per-CSR-slot edge table {e, si, di, sc}
__global__ __launch_bounds__(256) void scatter_kernel(
    const int* __restrict__ esrc, const int* __restrict__ edst,
    const float* __restrict__ tw, const float* __restrict__ mns,
    int* __restrict__ cursor, int4* __restrict__ etab) {
  const int e = blockIdx.x * 256 + threadIdx.x;
  const int si = esrc[e];
  const int di = edst[e];
  const int pos = atomicAdd(&cursor[di], 1);
  const float sc = tw[e] * 0.5f * (mns[si] + mns[di]);
  int4 v;
  v.x = e;
  v.y = si;
  v.z = di;
  v.w = __float_as_int(sc);
  etab[pos] = v;
}

// ---- edge kernel: 64 CSR-ordered edges/block; 8 waves = 2 Mg x 4 Ng
// (M=32, N=32 each); identity-B MFMA folds pg/pm LDS tiles into accumulators.
__global__ __launch_bounds__(512, 6) void edge_kernel(
    const float* __restrict__ emb, const int4* __restrict__ etab,
    const unsigned short* __restrict__ pd,
    const unsigned short* __restrict__ psm,
    const unsigned short* __restrict__ wts, const float* __restrict__ msgb1,
    const float* __restrict__ msgb2, const float* __restrict__ gateb1,
    const float* __restrict__ gateW2, const float* __restrict__ gateb2v,
    float* __restrict__ erout, float* __restrict__ aggf) {
  // pg 0..16384 | pm/t1 16384..32768 | emb 32768..40960 ;
  // f32 xbuf [64][132] (33792 B) aliases pg+pm+emb-front in the epilogue.
  __shared__ __align__(16) char buf[64 * 256 + 64 * 256 + 64 * 128];
  __shared__ float p_s[4][64];
  __shared__ float G_s[64];
  __shared__ float sc_s[64];
  __shared__ int di_s[64], eidx_s[64];

  char* pgp = buf;
  char* pmp = buf + 16384;
  char* embp = buf + 32768;
  float* xbuf = (float*)buf;

  const int tid = threadIdx.x;
  const int lane = tid & 63;
  const int wid = tid >> 6;
  const int q = lane >> 4;
  const int r16 = lane & 15;
  const int koff = q * 8;
  const int mg = wid >> 2;  // 0..1
  const int ng = wid & 3;   // 0..3
  const int e0 = blockIdx.x * 64;  // CSR positions; 12500*64 == NEDGE

  const unsigned short* gateW1T = wts + 73728;  // [128][320]
  const unsigned short* msgW1T = wts + 32768;   // [128][192]
  const unsigned short* msgW2T = wts + 57344;   // [128][128]

  // ---- per-edge scalars (consumed only after barrier 1)
  if (tid < 64) {
    const int4 et = etab[e0 + tid];
    eidx_s[tid] = et.x;
    di_s[tid] = et.z;
    sc_s[tid] = __int_as_float(et.w);
  }

  // ---- stage pg = bf16(Pd[di]+Ps[si]) (b128 writes), pm = Pm[si], emb->bf16
#pragma unroll
  for (int r = 0; r < 2; r++) {
    const int unit = tid + 512 * r;  // 0..1023 = 64 rows x 16 chunks
    const int row = unit >> 4;
    const int c = unit & 15;
    const int4 et = etab[e0 + row];
    const int si = et.y, di = et.z;
    const short8 vd = ld8(pd + (size_t)di * 128 + c * 8);
    const short8 vs = ld8(psm + (size_t)si * 256 + c * 8);
    union { unsigned int u[4]; short8 s; } pk;
#pragma unroll
    for (int h = 0; h < 4; h++) {
      const float f0 =
          bf2f((unsigned short)vd[2 * h]) + bf2f((unsigned short)vs[2 * h]);
      const float f1 = bf2f((unsigned short)vd[2 * h + 1]) +
                       bf2f((unsigned short)vs[2 * h + 1]);
      pk.u[h] = cvtpk(f0, f1);
    }
    *reinterpret_cast<short8*>(pgp + swz256(row, c * 16)) = pk.s;
    *reinterpret_cast<short8*>(pmp + swz256(row, c * 16)) =
        ld8(psm + (size_t)si * 256 + 128 + c * 8);
  }
#pragma unroll
  for (int r = 0; r < 2; r++) {
    const int unit = tid + 512 * r;  // 0..1023 = 64 rows x 16 f32x4 chunks
    const int row = unit >> 4;
    const int c4 = unit & 15;
    const int e = etab[e0 + row].x;
    const f32x4 v =
        *reinterpret_cast<const f32x4*>(emb + (size_t)e * 64 + c4 * 4);
    uint2 w;
    w.x = cvtpk(v[0], v[1]);
    w.y = cvtpk(v[2], v[3]);
    *reinterpret_cast<uint2*>(embp + swz128(row, c4 * 8)) = w;
  }
  __syncthreads();  // (1) tiles + scalars ready

  int cc[2];
  float g1[2], w2[2], b1m[2], b2m[2];
#pragma unroll
  for (int i = 0; i < 2; i++) {
    cc[i] = ng * 32 + i * 16 + r16;
    g1[i] = gateb1[cc[i]];
    w2[i] = gateW2[cc[i]];
    b1m[i] = msgb1[cc[i]];
    b2m[i] = msgb2[cc[i]];
  }

  // identity-B fragments: bI[i][h] = 1.0bf16 iff (q*8+h == i*16 + r16).
  short8 bI[2];
#pragma unroll
  for (int h = 0; h < 8; h++) {
    const int kk = koff + h;
    bI[0][h] = (kk == r16) ? (short)0x3F80 : (short)0;
    bI[1][h] = (kk == r16 + 16) ? (short)0x3F80 : (short)0;
  }

  f32x4 accg[2][2], acc1[2][2];
#pragma unroll
  for (int m = 0; m < 2; m++)
#pragma unroll
    for (int i = 0; i < 2; i++) {
      accg[m][i] = (f32x4){0.f, 0.f, 0.f, 0.f};
      acc1[m][i] = (f32x4){0.f, 0.f, 0.f, 0.f};
    }

  // ---- fold pg into accg and pm into acc1 via @Identity.
  // This wave's output cols (ng*32 + i*16 + r16) live in K-window ng*32:
  // one b128 LDS read + 2 MFMA per row-tile adds pg[row][col] exactly.
  {
    const int kw = ng * 32 + koff;
#pragma unroll
    for (int m = 0; m < 2; m++) {
      const int row = mg * 32 + m * 16 + r16;
      const short8 apg =
          *reinterpret_cast<const short8*>(pgp + swz256(row, kw * 2));
      const short8 apm =
          *reinterpret_cast<const short8*>(pmp + swz256(row, kw * 2));
#pragma unroll
      for (int i = 0; i < 2; i++) {
        accg[m][i] = MFMA(apg, bI[i], accg[m][i]);
        acc1[m][i] = MFMA(apm, bI[i], acc1[m][i]);
      }
    }
  }

  // ---- emb GEMMs: accg += emb@We (K=64), acc1 += emb@Me (K=64)
#pragma unroll
  for (int s = 0; s < 2; s++) {
    const int k0 = s * 32 + koff;  // 0..63
    short8 a[2];
#pragma unroll
    for (int m = 0; m < 2; m++)
      a[m] = *reinterpret_cast<const short8*>(
          embp + swz128(mg * 32 + m * 16 + r16, k0 * 2));
#pragma unroll
    for (int i = 0; i < 2; i++) {
      const short8 bg = ld8(gateW1T + cc[i] * 320 + 256 + k0);
      const short8 bm = ld8(msgW1T + cc[i] * 192 + 128 + k0);
#pragma unroll
      for (int m = 0; m < 2; m++) {
        accg[m][i] = MFMA(a[m], bg, accg[m][i]);
        acc1[m][i] = MFMA(a[m], bm, acc1[m][i]);
      }
    }
  }

  // ---- gate partials over this wave's 32 cols (no LDS reads)
#pragma unroll
  for (int m = 0; m < 2; m++) {
#pragma unroll
    for (int j = 0; j < 4; j++) {
      const int row = mg * 32 + m * 16 + q * 4 + j;
      float v = geluf(accg[m][0][j] + g1[0]) * w2[0] +
                geluf(accg[m][1][j] + g1[1]) * w2[1];
      v += __shfl_xor(v, 1);
      v += __shfl_xor(v, 2);
      v += __shfl_xor(v, 4);
      v += __shfl_xor(v, 8);
      if (r16 == 0) p_s[ng][row] = v;
    }
  }

  // ---- t1 = gelu(acc1 + b1) -> write-only into pm tile (wave-local subtile)
#pragma unroll
  for (int m = 0; m < 2; m++) {
#pragma unroll
    for (int i = 0; i < 2; i++) {
#pragma unroll
      for (int j = 0; j < 4; j++) {
        const int row = mg * 32 + m * 16 + q * 4 + j;
        *reinterpret_cast<unsigned short*>(pmp + swz256(row, cc[i] * 2)) =
            f2bf1(geluf(acc1[m][i][j] + b1m[i]));
      }
    }
  }
  __syncthreads();  // (2) t1 + p_s ready; pg reads done

  // ---- G combine (runs alongside GEMM2)
  if (tid < 64) {
    const float p = gateb2v[0] + p_s[0][tid] + p_s[1][tid] + p_s[2][tid] +
                    p_s[3][tid];
    G_s[tid] =
        sc_s[tid] * __builtin_amdgcn_rcpf(1.f + exp2f(-1.4426950f * p));
  }

  // ---- msg GEMM2: t1 @ msgW2, K=128
  f32x4 acc2[2][2];
#pragma unroll
  for (int m = 0; m < 2; m++)
#pragma unroll
    for (int i = 0; i < 2; i++) acc2[m][i] = (f32x4){0.f, 0.f, 0.f, 0.f};
#pragma unroll
  for (int s = 0; s < 4; s++) {
    const int k0 = s * 32 + koff;
    short8 a[2];
#pragma unroll
    for (int m = 0; m < 2; m++)
      a[m] = *reinterpret_cast<const short8*>(
          pmp + swz256(mg * 32 + m * 16 + r16, k0 * 2));
#pragma unroll
    for (int i = 0; i < 2; i++) {
      const short8 b = ld8(msgW2T + cc[i] * 128 + k0);
#pragma unroll
      for (int m = 0; m < 2; m++) acc2[m][i] = MFMA(a[m], b, acc2[m][i]);
    }
  }
  __syncthreads();  // (3) all t1/emb reads done; G_s ready; xbuf safe

  // ---- epilogue: scale + single-pass transpose into xbuf[64][132]
#pragma unroll
  for (int m = 0; m < 2; m++)
#pragma unroll
    for (int i = 0; i < 2; i++)
#pragma unroll
      for (int j = 0; j < 4; j++) {
        const int row = mg * 32 + m * 16 + q * 4 + j;
        xbuf[row * 132 + cc[i]] = G_s[row] * (acc2[m][i][j] + b2m[i]);
      }
  __syncthreads();  // (4) xbuf complete

  // full-line float4 stores to the (original edge id) output rows
#pragma unroll
  for (int u = 0; u < 4; u++) {
    const int unit = tid + u * 512;  // 0..2047 = 64 rows x 32 f4-chunks
    const int r = unit >> 5;
    const int f4 = unit & 31;
    const f32x4 val = *reinterpret_cast<const f32x4*>(&xbuf[r * 132 + f4 * 4]);
    *reinterpret_cast<f32x4*>(erout + (size_t)eidx_s[r] * 128 + f4 * 4) = val;
  }

  // segmented column-walk aggregation (rows are dst-sorted):
  // 512 threads = 128 cols x 4 sixteen-row quarters; ~1-3 flushes per quarter.
  {
    const int col = tid & 127;
    const int qt = tid >> 7;  // 0..3
    const int rbeg = qt * 16, rend = rbeg + 16;
    float acc = 0.f;
    int prev = di_s[rbeg];
    for (int r = rbeg; r < rend; ++r) {
      const int d = di_s[r];
      if (d != prev) {
        atomicAdd(&aggf[(size_t)prev * 128 + col], acc);
        acc = 0.f;
        prev = d;
      }
      acc += xbuf[r * 132 + col];
    }
    atomicAdd(&aggf[(size_t)prev * 128 + col], acc);
  }
}

// ---- fused node update + FFN:
// out1 = x + LN1(x)@selfW + selfb + (agg/deg)@aggW + aggb   (registers only)
// out  = out1 + gelu(LN2(out1)@W1 + b1)@W2 + b2
__global__ __launch_bounds__(256) void node_ffn_kernel(
    const float* __restrict__ x, const float* __restrict__ ln1g,
    const float* __restrict__ ln1b, const float* __restrict__ aggf,
    const int* __restrict__ row_start, const unsigned short* __restrict__ wts,
    const float* __restrict__ selfb, const float* __restrict__ aggb,
    const float* __restrict__ ln2g, const float* __restrict__ ln2b,
    const float* __restrict__ fb1, const float* __restrict__ fb2,
    float* __restrict__ outp) {
  __shared__ unsigned short h2s[4][16 * 136];  // LN2 output per wave
  __shared__ unsigned short ts[4][16 * 264];   // gelu(t) per wave
  const int wid = threadIdx.x >> 6, lane = threadIdx.x & 63;
  const int q = lane >> 4, r16 = lane & 15, koff = q * 8;
  const int r0 = blockIdx.x * 64 + wid * 16;
  const int row = min(r0 + r16, NN - 1);
  const float inv = __builtin_amdgcn_rcpf(
      fmaxf((float)(row_start[row + 1] - row_start[row]), 1.0f));
  const unsigned short* selfWT = wts;
  const unsigned short* aggWT = wts + 16384;
  const unsigned short* W1T = wts + 114688;  // [256][128]
  const unsigned short* W2T = wts + 147456;  // [128][256]

  // ---- node1 GEMMs
  short8 a1[4];
  ln_frags(x + (size_t)row * 128, ln1g, ln1b, koff, a1);
  f32x4 acc[8];
#pragma unroll
  for (int nt = 0; nt < 8; nt++) acc[nt] = (f32x4){0.f, 0.f, 0.f, 0.f};
#pragma unroll
  for (int s = 0; s < 4; s++) {
    const int k0 = s * 32 + koff;
    const float* ap = aggf + (size_t)row * 128 + k0;
    const f32x4 f0 = *reinterpret_cast<const f32x4*>(ap);
    const f32x4 f1 = *reinterpret_cast<const f32x4*>(ap + 4);
    union { unsigned int u[4]; short8 s; } pk;
    pk.u[0] = cvtpk(f0[0] * inv, f0[1] * inv);
    pk.u[1] = cvtpk(f0[2] * inv, f0[3] * inv);
    pk.u[2] = cvtpk(f1[0] * inv, f1[1] * inv);
    pk.u[3] = cvtpk(f1[2] * inv, f1[3] * inv);
#pragma unroll
    for (int nt = 0; nt < 8; nt++) {
      acc[nt] = MFMA(a1[s], ld8(selfWT + (nt * 16 + r16) * 128 + k0), acc[nt]);
      acc[nt] = MFMA(pk.s, ld8(aggWT + (nt * 16 + r16) * 128 + k0), acc[nt]);
    }
  }

  // ---- out1 in registers (C/D layout: o[nt][j], col = nt*16+r16, row q*4+j)
  float o[8][4];
#pragma unroll
  for (int j = 0; j < 4; j++) {
    const int gr = min(r0 + q * 4 + j, NN - 1);
#pragma unroll
    for (int nt = 0; nt < 8; nt++) {
      const int c = r16 + 16 * nt;
      o[nt][j] = x[(size_t)gr * 128 + c] + acc[nt][j] + selfb[c] + aggb[c];
    }
  }

  // ---- LN2 in C/D layout (reduce over 16 r16-lanes x 8 nt) -> h2s bf16
#pragma unroll
  for (int j = 0; j < 4; j++) {
    float s1 = 0.f;
#pragma unroll
    for (int nt = 0; nt < 8; nt++) s1 += o[nt][j];
    s1 += __shfl_xor(s1, 1);
    s1 += __shfl_xor(s1, 2);
    s1 += __shfl_xor(s1, 4);
    s1 += __shfl_xor(s1, 8);
    const float mean = s1 * 0.0078125f;
    float s2 = 0.f;
#pragma unroll
    for (int nt = 0; nt < 8; nt++) {
      const float d = o[nt][j] - mean;
      s2 += d * d;
    }
    s2 += __shfl_xor(s2, 1);
    s2 += __shfl_xor(s2, 2);
    s2 += __shfl_xor(s2, 4);
    s2 += __shfl_xor(s2, 8);
    const float rs = rsqrtf(s2 * 0.0078125f + 1e-5f);
#pragma unroll
    for (int nt = 0; nt < 8; nt++) {
      const int c = r16 + 16 * nt;
      h2s[wid][(q * 4 + j) * 136 + c] =
          f2bf1((o[nt][j] - mean) * rs * ln2g[c] + ln2b[c]);
    }
  }
  // wave-local LDS dep (writer lanes != reader lanes but same wave: lgkmcnt)

  // ---- FFN GEMM1: h2 @ W1 (K=128, N=256)
  f32x4 acc1[16];
#pragma unroll
  for (int nt = 0; nt < 16; nt++) acc1[nt] = (f32x4){0.f, 0.f, 0.f, 0.f};
#pragma unroll
  for (int s = 0; s < 4; s++) {
    const int k0 = s * 32 + koff;
    const short8 a =
        *reinterpret_cast<const short8*>(&h2s[wid][r16 * 136 + k0]);
#pragma unroll
    for (int nt = 0; nt < 16; nt++)
      acc1[nt] = MFMA(a, ld8(W1T + (nt * 16 + r16) * 128 + k0), acc1[nt]);
  }
#pragma unroll
  for (int nt = 0; nt < 16; nt++) {
    const int c = r16 + 16 * nt;
    const float bb = fb1[c];
#pragma unroll
    for (int j = 0; j < 4; j++)
      ts[wid][(q * 4 + j) * 264 + c] = f2bf1(geluf(acc1[nt][j] + bb));
  }

  // ---- FFN GEMM2: t @ W2 (K=256, N=128), wave-local ts
  f32x4 acc2[8];
#pragma unroll
  for (int nt = 0; nt < 8; nt++) acc2[nt] = (f32x4){0.f, 0.f, 0.f, 0.f};
#pragma unroll
  for (int s = 0; s < 8; s++) {
    const int k0 = s * 32 + koff;
    const short8 av =
        *reinterpret_cast<const short8*>(&ts[wid][r16 * 264 + k0]);
#pragma unroll
    for (int nt = 0; nt < 8; nt++)
      acc2[nt] = MFMA(av, ld8(W2T + (nt * 16 + r16) * 256 + k0), acc2[nt]);
  }

  // ---- final: out = out1 + ffn + b2
#pragma unroll
  for (int j = 0; j < 4; j++) {
    const int gr = r0 + q * 4 + j;
    if (gr < NN) {
#pragma unroll
      for (int nt = 0; nt < 8; nt++) {
        const int c = r16 + 16 * nt;
        outp[(size_t)gr * 128 + c] = o[nt][j] + acc2[nt][j] + fb2[c];
      }
    }
  }
}

extern "C" void kernel_launch(void* const* d_in, const int* in_sizes, int n_in,
                              void* d_out, int out_size, void* d_ws,
                              size_t ws_size, hipStream_t stream) {
  (void)in_sizes; (void)n_in; (void)out_size; (void)ws_size;
  const float* x = (const float*)d_in[0];
  const float* emb = (const float*)d_in[1];
  const float* tw = (const float*)d_in[2];
  const float* mns = (const float*)d_in[3];
  const float* ln1g = (const float*)d_in[4];
  const float* ln1b = (const float*)d_in[5];
  const float* ln2g = (const float*)d_in[6];
  const float* ln2b = (const float*)d_in[7];
  const float* selfW = (const float*)d_in[8];
  const float* selfb = (const float*)d_in[9];
  const float* msgW1 = (const float*)d_in[10];
  const float* msgb1 = (const float*)d_in[11];
  const float* msgW2 = (const float*)d_in[12];
  const float* msgb2 = (const float*)d_in[13];
  const float* gateW1 = (const float*)d_in[14];
  const float* gateb1 = (const float*)d_in[15];
  const float* gateW2 = (const float*)d_in[16];
  const float* gateb2 = (const float*)d_in[17];
  const float* aggW = (const float*)d_in[18];
  const float* aggb = (const float*)d_in[19];
  const float* ffnW1 = (const float*)d_in[20];
  const float* ffnb1 = (const float*)d_in[21];
  const float* ffnW2 = (const float*)d_in[22];
  const float* ffnb2 = (const float*)d_in[23];
  const int* esrc = (const int*)d_in[24];
  const int* edst = (const int*)d_in[25];

  // ws layout (bytes):
  // Pd 0..12.8M | Psm 25.6M..51.2M | wts 76.8M+360448 | cnt 77,160,448 |
  // row_start 77,360,640 | cursor 77,560,832 | bsum 77,761,024 |
  // etab 77,763,072 +12.8M (~90.6 MB)
  // agg accumulator lives in d_out's NODE region (dead until node_ffn).
  char* ws = (char*)d_ws;
  unsigned short* pdb = (unsigned short*)(ws);
  unsigned short* psmb = (unsigned short*)(ws + 25600000);
  unsigned short* wts = (unsigned short*)(ws + 76800000);
  int* cnt = (int*)(ws + 77160448);
  int* row_start = (int*)(ws + 77360640);
  int* cursor = (int*)(ws + 77560832);
  int* bsum = (int*)(ws + 77761024);
  int4* etab = (int4*)(ws + 77763072);

  float* out_nodes = (float*)d_out;
  float* out_edges = out_nodes + (size_t)NN * 128;
  float* aggf = out_nodes;  // reused as f32 accumulator until node_ffn

  const int NB_SCAN = (NN + 255) / 256;  // 196

  prep_kernel<<<704, 256, 0, stream>>>(selfW, msgW1, msgW2, gateW1, aggW,
                                       ffnW1, ffnW2, wts, cnt);
  node_pre_kernel<<<782, 256, 0, stream>>>(x, ln1g, ln1b, wts, edst, pdb,
                                           psmb, aggf, cnt);
  scan_sums_kernel<<<NB_SCAN, 256, 0, stream>>>(cnt, bsum);
  scan_final_kernel<<<NB_SCAN, 256, 0, stream>>>(cnt, bsum, row_start, cursor);
  scatter_kernel<<<3125, 256, 0, stream>>>(esrc, edst, tw, mns, cursor, etab);
  edge_kernel<<<12500, 512, 0, stream>>>(emb, etab, pdb, psmb, wts, msgb1,
                                         msgb2, gateb1, gateW2, gateb2,
                                         out_edges, aggf);
  node_ffn_kernel<<<782, 256, 0, stream>>>(x, ln1g, ln1b, aggf, row_start,
                                           wts, selfb, aggb, ln2g, ln2b,
                                           ffnb1, ffnb2, out_nodes);
}